// Round 5
// baseline (82.795 us; speedup 1.0000x reference)
//
#include <hip/hip_runtime.h>

// Resample 48k -> 10k: up=5, down=24, 481-tap FIR.
// y[5k+d] = sum_{w=0}^{119} T[wg,d,u] * x[24k-48+w],  w=8*wg+u
// T[wg*40+d*8+u] = 5*h[24d+480-5w]  (wave-uniform per group)
//
// KEY CHANGE (R5): taps live in LDS, not global/SMEM. Previously the
// wave-uniform tap reads compiled to s_load_dwordx8; SMEM completes
// out-of-order vs DS but shares lgkmcnt, forcing conservative
// lgkmcnt(0) drains between every tap group and its FMAs (~15 drains
// x ~200cy per step, identical in R1/R3/R4 -> the invariant ~70us).
// Tap reads are now same-address ds_read_b128 broadcasts (conflict-free),
// lgkmcnt is DS-only/in-order -> compiler emits counted waits.
//
// LDS budget: x pad-2-per-8 (conflict-free b64 window reads) 29.3 kB
// + 2.4 kB taps = 31.7 kB -> 5 blocks/CU (158.4 <= 160 kB).
// BK=240: 250 blocks/row * 240 = 60000 exactly.

#define NIN   1440000
#define NOUTR 300000
#define NROWS 32
#define KTOT  60000
#define BK    240
#define NBLK  250                      // 250*240 == KTOT
#define TILE  (24*(BK-1)+120)          // 5856 floats
#define NV4   (TILE/4)                 // 1464 float4s
#define LDSX  (TILE + (TILE/8)*2)      // 7320 floats: swizzled x region
#define TAPN  600
#define LDSN  (LDSX + TAPN)            // 7920 floats = 31680 B

// T[wg*40 + d*8 + u] = 5 * h[24d + 480 - 5*(wg*8+u)]  (0 outside [0,480])
__global__ void prep_taps_kernel(const float* __restrict__ h, float* __restrict__ T) {
    int i = blockIdx.x * blockDim.x + threadIdx.x;
    if (i < TAPN) {
        int u  = i & 7;
        int d  = (i >> 3) % 5;
        int wg = i / 40;
        int t  = 24 * d + 480 - 5 * (wg * 8 + u);
        T[i] = (t >= 0 && t <= 480) ? h[t] * 5.0f : 0.0f;
    }
}

__global__ __launch_bounds__(256) void resample_kernel(
    const float* __restrict__ x, const float* __restrict__ T, float* __restrict__ y)
{
    __shared__ float lds[LDSN];
    const int tid = threadIdx.x;
    const int row = blockIdx.y;
    const int k0  = blockIdx.x * BK;
    const float* __restrict__ xr = x + (size_t)row * NIN;
    const int g0 = 24 * k0 - 48;

    // Stage taps: 600 floats, float4 loads + stores (LDSX*4 = 29280 B, 16B-aligned).
    if (tid < TAPN / 4) {
        const float4 t4 = *reinterpret_cast<const float4*>(T + 4 * tid);
        *reinterpret_cast<float4*>(&lds[LDSX + 4 * tid]) = t4;
    }

    // Stage x tile, pad-2-per-8 swizzle (m = e + (e>>3)*2): window chunks
    // e0=24t+8wg -> m0=30t+10wg, 8 contiguous floats -> 4x ds_read_b64,
    // bank-pair (15t+5wg+c) mod 16 conflict-free.
    if (g0 >= 0 && g0 + TILE <= NIN) {          // uniform fast path
        for (int i4 = tid; i4 < NV4; i4 += 256) {
            const int e = i4 * 4;
            const float4 v = *reinterpret_cast<const float4*>(xr + g0 + e);
            const int m = e + ((e >> 3) << 1);
            *reinterpret_cast<float2*>(&lds[m])     = make_float2(v.x, v.y);
            *reinterpret_cast<float2*>(&lds[m + 2]) = make_float2(v.z, v.w);
        }
    } else {                                     // first/last block only
        for (int i4 = tid; i4 < NV4; i4 += 256) {
            const int e = i4 * 4;
            const int g = g0 + e;
            float4 v;
            v.x = ((unsigned)(g + 0) < NIN) ? xr[g + 0] : 0.0f;
            v.y = ((unsigned)(g + 1) < NIN) ? xr[g + 1] : 0.0f;
            v.z = ((unsigned)(g + 2) < NIN) ? xr[g + 2] : 0.0f;
            v.w = ((unsigned)(g + 3) < NIN) ? xr[g + 3] : 0.0f;
            const int m = e + ((e >> 3) << 1);
            *reinterpret_cast<float2*>(&lds[m])     = make_float2(v.x, v.y);
            *reinterpret_cast<float2*>(&lds[m + 2]) = make_float2(v.z, v.w);
        }
    }
    __syncthreads();

    if (tid < BK) {
        float acc0 = 0.f, acc1 = 0.f, acc2 = 0.f, acc3 = 0.f, acc4 = 0.f;
        const int base = 30 * tid;
        #pragma unroll
        for (int wg = 0; wg < 15; ++wg) {
            const int m0 = base + 10 * wg;
            const float2 p0 = *reinterpret_cast<const float2*>(&lds[m0]);
            const float2 p1 = *reinterpret_cast<const float2*>(&lds[m0 + 2]);
            const float2 p2 = *reinterpret_cast<const float2*>(&lds[m0 + 4]);
            const float2 p3 = *reinterpret_cast<const float2*>(&lds[m0 + 6]);
            const float xv[8] = {p0.x, p0.y, p1.x, p1.y, p2.x, p2.y, p3.x, p3.y};
            const float* __restrict__ tp = &lds[LDSX + wg * 40];
            #pragma unroll
            for (int d = 0; d < 5; ++d) {
                // compile-time skip of all-zero tap groups (wg,d constants)
                if (24 * d + 480 - 40 * wg >= 0 && 24 * d + 445 - 40 * wg <= 480) {
                    // uniform-address b128 broadcasts, conflict-free
                    const float4 ta = *reinterpret_cast<const float4*>(&tp[d * 8]);
                    const float4 tb = *reinterpret_cast<const float4*>(&tp[d * 8 + 4]);
                    float a = (d == 0) ? acc0 : (d == 1) ? acc1 : (d == 2) ? acc2
                            : (d == 3) ? acc3 : acc4;
                    a += ta.x * xv[0] + ta.y * xv[1] + ta.z * xv[2] + ta.w * xv[3]
                       + tb.x * xv[4] + tb.y * xv[5] + tb.z * xv[6] + tb.w * xv[7];
                    if      (d == 0) acc0 = a;
                    else if (d == 1) acc1 = a;
                    else if (d == 2) acc2 = a;
                    else if (d == 3) acc3 = a;
                    else             acc4 = a;
                }
            }
        }

        const int k = k0 + tid;                  // always < KTOT (250*240 exact)
        float* __restrict__ yr = y + (size_t)row * NOUTR + (size_t)5 * k;
        yr[0] = acc0; yr[1] = acc1; yr[2] = acc2; yr[3] = acc3; yr[4] = acc4;
    }
}

extern "C" void kernel_launch(void* const* d_in, const int* in_sizes, int n_in,
                              void* d_out, int out_size, void* d_ws, size_t ws_size,
                              hipStream_t stream) {
    const float* x = (const float*)d_in[0];
    const float* h = (const float*)d_in[1];   // 481 taps
    float* y = (float*)d_out;                 // 32 x 300000 f32
    float* T = (float*)d_ws;                  // 600 floats of scratch

    prep_taps_kernel<<<3, 256, 0, stream>>>(h, T);
    dim3 grid(NBLK, NROWS);                   // 250 x 32
    resample_kernel<<<grid, 256, 0, stream>>>(x, T, y);
}